// Round 2
// baseline (3573.576 us; speedup 1.0000x reference)
//
#include <hip/hip_runtime.h>
#include <hip/hip_bf16.h>
#include <stdint.h>

// Sizes (fixed by the problem)
#define BATCH 64
#define SEQ   4096
#define CIN   128
#define F     64      // LATENT
#define GATES 256     // 4*F
#define NF    10
#define NSLOT 16      // h0 ring slots per batch (chunks of 16 ticks)

// ---------------- ws layout (requires ws_size >= 71,319,552 B; round-1 ran with 100.7MB) ----------------
// cv    : f32 [B][S][F]        conv stack output   67,108,864 B @ 0
// h0ring: f32 [B][NSLOT][16][F]                      4,194,304 B @ 67,108,864
// flags : prod u32/batch @128B (8KB), cons (8KB)       16,384 B @ 71,303,168
#define CV_OFF    0ull
#define RING_OFF  67108864ull
#define FLAGS_OFF 71303168ull

static __device__ __forceinline__ float sigm(float x) {
  return 1.0f / (1.0f + __expf(-x));
}
static __device__ __forceinline__ float tanh_f(float x) {
  float e = __expf(2.0f * x);           // graceful at +-inf
  return 1.0f - 2.0f / (e + 1.0f);
}

// ---------------- fused 3-stage conv1d (k=3, SAME) + ReLU ----------------
// One WG computes 64 output positions for one batch. Halo rows are recomputed,
// but any row whose ABSOLUTE position is outside [0,SEQ) is forced to 0 to
// match the reference's per-layer zero padding (round-1 bug fix).
template<int NIN, int NROWS, bool TOG>
static __device__ __forceinline__ void conv_stage(
    const float* in, const float* __restrict__ w, const float* __restrict__ bias,
    float* out, float* gout, int gbase, int tbase)
{
  const int tid = threadIdx.x;
  const int cb = (tid & 15) << 2;   // out-channel base (4 per thread)
  const int pg = tid >> 4;          // row phase 0..15
  constexpr int M = (NROWS + 15) / 16;
  float acc[M][4];
#pragma unroll
  for (int m = 0; m < M; ++m) { acc[m][0] = acc[m][1] = acc[m][2] = acc[m][3] = 0.f; }
#pragma unroll 1
  for (int cc = 0; cc < NIN; cc += 8) {
    float wr[3][8][4];
#pragma unroll
    for (int k = 0; k < 3; ++k)
#pragma unroll
      for (int ci = 0; ci < 8; ++ci) {
        const float4 t = *(const float4*)&w[(k * NIN + cc + ci) * F + cb];
        wr[k][ci][0] = t.x; wr[k][ci][1] = t.y; wr[k][ci][2] = t.z; wr[k][ci][3] = t.w;
      }
#pragma unroll
    for (int m = 0; m < M; ++m) {
      const int r = pg + 16 * m;
      if ((M * 16 == NROWS) || (r < NROWS)) {
#pragma unroll
        for (int k = 0; k < 3; ++k) {
          const float* row = &in[(r + k) * NIN + cc];
          const float4 a  = *(const float4*)&row[0];
          const float4 b4 = *(const float4*)&row[4];
          const float xv[8] = {a.x, a.y, a.z, a.w, b4.x, b4.y, b4.z, b4.w};
#pragma unroll
          for (int ci = 0; ci < 8; ++ci) {
            acc[m][0] += xv[ci] * wr[k][ci][0];
            acc[m][1] += xv[ci] * wr[k][ci][1];
            acc[m][2] += xv[ci] * wr[k][ci][2];
            acc[m][3] += xv[ci] * wr[k][ci][3];
          }
        }
      }
    }
  }
  const float4 bv = *(const float4*)&bias[cb];
#pragma unroll
  for (int m = 0; m < M; ++m) {
    const int r = pg + 16 * m;
    if ((M * 16 == NROWS) || (r < NROWS)) {
      const bool ok = (unsigned)(tbase + r) < (unsigned)SEQ;  // per-layer zero padding
      const float o0 = ok ? fmaxf(acc[m][0] + bv.x, 0.f) : 0.f;
      const float o1 = ok ? fmaxf(acc[m][1] + bv.y, 0.f) : 0.f;
      const float o2 = ok ? fmaxf(acc[m][2] + bv.z, 0.f) : 0.f;
      const float o3 = ok ? fmaxf(acc[m][3] + bv.w, 0.f) : 0.f;
      if (TOG) {
        *(float4*)&gout[gbase + r * F + cb] = make_float4(o0, o1, o2, o3);
      } else {
        *(float4*)&out[r * F + cb] = make_float4(o0, o1, o2, o3);
      }
    }
  }
}

__global__ __launch_bounds__(256, 2) void conv_fused(
    const float* __restrict__ x,
    const float* __restrict__ w0, const float* __restrict__ b0,
    const float* __restrict__ w1, const float* __restrict__ b1,
    const float* __restrict__ w2, const float* __restrict__ b2,
    float* __restrict__ cv)
{
  __shared__ __align__(16) float xs[70][CIN];   // x[t0-3 .. t0+66]
  __shared__ __align__(16) float y0s[68][F];    // y0[t0-2 .. t0+65]
  __shared__ __align__(16) float y1s[66][F];    // y1[t0-1 .. t0+64]
  const int wg  = blockIdx.x;
  const int b   = wg >> 6;
  const int t0  = (wg & 63) << 6;
  const int tid = threadIdx.x;

  const float* xb = x + (size_t)b * SEQ * CIN;
  for (int i = tid; i < 70 * (CIN / 4); i += 256) {
    const int r  = i >> 5;
    const int c4 = (i & 31) << 2;
    const int t  = t0 - 3 + r;
    float4 v = make_float4(0.f, 0.f, 0.f, 0.f);
    if ((unsigned)t < (unsigned)SEQ) v = *(const float4*)&xb[(size_t)t * CIN + c4];
    *(float4*)&xs[r][c4] = v;
  }
  __syncthreads();
  conv_stage<CIN, 68, false>(&xs[0][0], w0, b0, &y0s[0][0], nullptr, 0, t0 - 2);
  __syncthreads();
  conv_stage<F, 66, false>(&y0s[0][0], w1, b1, &y1s[0][0], nullptr, 0, t0 - 1);
  __syncthreads();
  conv_stage<F, 64, true>(&y1s[0][0], w2, b2, nullptr, cv, (b * SEQ + t0) * F, t0);
}

// ---------------- persistent LSTM scan ----------------
// Grid = 128 WGs x 256 threads. WG < 64: layer-0 producer (batch = wg), reads
// fp32 conv output, publishes h0 chunks (16 ticks) into a 16-slot ring with
// release flags. WG >= 64: layer-1 consumer; acquires chunks, frees slots via
// a consumed-counter (backpressure), keeps c1 private, writes dense head.
__global__ __launch_bounds__(256, 1) void lstm_scan(
    const float* __restrict__ cv,
    float* __restrict__ ring, uint32_t* __restrict__ flags,
    const float* __restrict__ Wx0, const float* __restrict__ Wh0, const float* __restrict__ bl0,
    const float* __restrict__ Wx1, const float* __restrict__ Wh1, const float* __restrict__ bl1,
    const float* __restrict__ dw, const float* __restrict__ db,
    float* __restrict__ out)
{
  const int  wg   = blockIdx.x;
  const bool prod = (wg < BATCH);
  const int  b    = prod ? wg : (wg - BATCH);
  const int  tid  = threadIdx.x;
  const int  q    = tid & 63;
  const int  kc   = tid >> 6;   // wave id 0..3

  __shared__ __align__(16) float xch[16][F];      // input chunk (16 ticks)
  __shared__ __align__(16) float hl[F];           // this layer's h state
  __shared__ __align__(16) float parts[4][4][F];  // [kc][gate][q]
  __shared__ __align__(16) float csave[F];

  const float* Wx = prod ? Wx0 : Wx1;
  const float* Wh = prod ? Wh0 : Wh1;
  const float* bb = prod ? bl0 : bl1;

  float wx[4][16], wh[4][16];
#pragma unroll
  for (int g = 0; g < 4; ++g)
#pragma unroll
    for (int kk = 0; kk < 16; ++kk) {
      const int k = (kc << 4) + kk;
      const int j = q + (g << 6);
      wx[g][kk] = Wx[k * GATES + j];
      wh[g][kk] = Wh[k * GATES + j];
    }
  float bias4[4] = {0.f, 0.f, 0.f, 0.f};
  if (tid < F) {
#pragma unroll
    for (int g = 0; g < 4; ++g) bias4[g] = bb[q + (g << 6)];
    hl[tid] = 0.f;
  }
  float creg = 0.f;
  __syncthreads();

  const float* xsrc = cv + (size_t)b * SEQ * F;
  float* myring = ring + (size_t)b * NSLOT * 16 * F;
  uint32_t* prodflag = flags + b * 32;            // 128B stride
  uint32_t* consflag = flags + 2048 + b * 32;     // second 8KB region

#pragma unroll 1
  for (int c = 0; c < SEQ / 16; ++c) {
    const int slot = c & (NSLOT - 1);
    // ---- stage chunk input into LDS (1024 floats, 4/thread) ----
    if (prod) {
      const float4 v = *(const float4*)&xsrc[c * 1024 + (tid << 2)];
      ((float4*)&xch[0][0])[tid] = v;
      // backpressure: wait until ring slot is free
      if (tid == 0) {
        while ((uint32_t)c >= NSLOT + __hip_atomic_load(consflag, __ATOMIC_ACQUIRE, __HIP_MEMORY_SCOPE_AGENT))
          __builtin_amdgcn_s_sleep(2);
      }
      __syncthreads();
    } else {
      while (__hip_atomic_load(prodflag, __ATOMIC_ACQUIRE, __HIP_MEMORY_SCOPE_AGENT) <= (uint32_t)c)
        __builtin_amdgcn_s_sleep(2);
      const float* src = myring + slot * 1024 + (tid << 2);
      float4 f4;
      f4.x = __hip_atomic_load(src + 0, __ATOMIC_RELAXED, __HIP_MEMORY_SCOPE_AGENT);
      f4.y = __hip_atomic_load(src + 1, __ATOMIC_RELAXED, __HIP_MEMORY_SCOPE_AGENT);
      f4.z = __hip_atomic_load(src + 2, __ATOMIC_RELAXED, __HIP_MEMORY_SCOPE_AGENT);
      f4.w = __hip_atomic_load(src + 3, __ATOMIC_RELAXED, __HIP_MEMORY_SCOPE_AGENT);
      ((float4*)&xch[0][0])[tid] = f4;
      __syncthreads();              // staging loads retired; slot content copied
      if (tid == 0)
        __hip_atomic_store(consflag, (uint32_t)(c + 1),
                           __ATOMIC_RELEASE, __HIP_MEMORY_SCOPE_AGENT);
    }
#pragma unroll 1
    for (int it = 0; it < 16; ++it) {
      // Phase A: partial gates (x-part + h-part), 128 FMA/thread
      float xv[16], hv[16];
      const float4* xp = (const float4*)&xch[it][kc << 4];
      const float4* hp = (const float4*)&hl[kc << 4];
#pragma unroll
      for (int u = 0; u < 4; ++u) {
        const float4 a = xp[u];
        xv[4*u] = a.x; xv[4*u+1] = a.y; xv[4*u+2] = a.z; xv[4*u+3] = a.w;
        const float4 h4 = hp[u];
        hv[4*u] = h4.x; hv[4*u+1] = h4.y; hv[4*u+2] = h4.z; hv[4*u+3] = h4.w;
      }
      float a0 = 0.f, a1 = 0.f, a2 = 0.f, a3 = 0.f;
#pragma unroll
      for (int kk = 0; kk < 16; ++kk) {
        a0 += xv[kk] * wx[0][kk]; a1 += xv[kk] * wx[1][kk];
        a2 += xv[kk] * wx[2][kk]; a3 += xv[kk] * wx[3][kk];
        a0 += hv[kk] * wh[0][kk]; a1 += hv[kk] * wh[1][kk];
        a2 += hv[kk] * wh[2][kk]; a3 += hv[kk] * wh[3][kk];
      }
      parts[kc][0][q] = a0; parts[kc][1][q] = a1;
      parts[kc][2][q] = a2; parts[kc][3][q] = a3;
      __syncthreads();
      // Phase B: combine + activations + state update (wave 0)
      if (tid < F) {
        const float s0 = parts[0][0][q] + parts[1][0][q] + parts[2][0][q] + parts[3][0][q] + bias4[0];
        const float s1 = parts[0][1][q] + parts[1][1][q] + parts[2][1][q] + parts[3][1][q] + bias4[1];
        const float s2 = parts[0][2][q] + parts[1][2][q] + parts[2][2][q] + parts[3][2][q] + bias4[2];
        const float s3 = parts[0][3][q] + parts[1][3][q] + parts[2][3][q] + parts[3][3][q] + bias4[3];
        const float iv = sigm(s0);
        const float fv = sigm(s1);
        const float gv = tanh_f(s2);
        const float ov = sigm(s3);
        creg = fv * creg + iv * gv;
        const float hnew = ov * tanh_f(creg);
        hl[q] = hnew;
        if (prod)
          __hip_atomic_store(&myring[slot * 1024 + it * F + q], hnew,
                             __ATOMIC_RELAXED, __HIP_MEMORY_SCOPE_AGENT);
      }
      __syncthreads();
    }
    if (prod && tid == 0)
      __hip_atomic_store(prodflag, (uint32_t)(c + 1),
                         __ATOMIC_RELEASE, __HIP_MEMORY_SCOPE_AGENT);
  }

  // ---- dense head from final c of layer 1 ----
  if (!prod) {
    if (tid < F) csave[q] = creg;
    __syncthreads();
    if (tid < NF) {
      float acc = db[tid];
#pragma unroll 1
      for (int f = 0; f < F; ++f) acc += csave[f] * dw[f * NF + tid];
      out[b * NF + tid] = acc;
    }
  }
}

extern "C" void kernel_launch(void* const* d_in, const int* in_sizes, int n_in,
                              void* d_out, int out_size, void* d_ws, size_t ws_size,
                              hipStream_t stream) {
  const float* x   = (const float*)d_in[0];
  const float* w0  = (const float*)d_in[1];
  const float* b0  = (const float*)d_in[2];
  const float* w1  = (const float*)d_in[3];
  const float* b1  = (const float*)d_in[4];
  const float* w2  = (const float*)d_in[5];
  const float* b2  = (const float*)d_in[6];
  const float* Wx0 = (const float*)d_in[7];
  const float* Wh0 = (const float*)d_in[8];
  const float* bl0 = (const float*)d_in[9];
  const float* Wx1 = (const float*)d_in[10];
  const float* Wh1 = (const float*)d_in[11];
  const float* bl1 = (const float*)d_in[12];
  const float* dw  = (const float*)d_in[13];
  const float* db  = (const float*)d_in[14];
  float* out = (float*)d_out;

  char* ws = (char*)d_ws;
  float*    cv    = (float*)(ws + CV_OFF);
  float*    ring  = (float*)(ws + RING_OFF);
  uint32_t* flags = (uint32_t*)(ws + FLAGS_OFF);

  hipMemsetAsync(flags, 0, 16384, stream);
  conv_fused<<<dim3(4096), dim3(256), 0, stream>>>(x, w0, b0, w1, b1, w2, b2, cv);
  lstm_scan<<<dim3(128), dim3(256), 0, stream>>>(cv, ring, flags,
                                                 Wx0, Wh0, bl0, Wx1, Wh1, bl1,
                                                 dw, db, out);
}